// Round 10
// baseline (66.287 us; speedup 1.0000x reference)
//
#include <hip/hip_runtime.h>

#define N_ROWS 128
#define IN_DIM 1024
#define OUT_DIM 1024

// out[n,o] = max_k(w[o,k] + x[n,k]) + bias[o]   (tropical matmul)
//
// R10 = R9 (w-in-LDS once per block, x-in-regs) + epilogue surgery.
// R9 ledger audit: k-reduce scratch = 64 b32 writes + 64 b32 reads per
// wave = ~740 LDS-pipe cyc/wave -> ~2.5 us/CU serialized: as costly as
// the whole main loop. Two fixes:
//  (1) og2 remap: wave split into 2 halves; half h covers o-rows
//      h*8..h*8+7, lane k-slice = 8 f4 {t*32+g}. Main-loop LDS/VALU
//      unchanged (full 1 KB useful per ds_read_b128); reduce width
//      64 -> 32 partials/output. acc[4][8]=32 regs, xr[4][8]=128.
//  (2) vectorized scratch: lane-row layout padded to 36 words
//      (16B-aligned, banks: write native b128, read (4s+v)%32 2-way
//      free) -> 8 ds_write_b128 + 32 ds_read_b32 = 40 instr/wave
//      (was 128), ~282 cyc.
// Everything else = R9: 512 blocks (8 bn x 64 bo, idx%8==bo%8 same-XCD),
// 256 thr, panel 64 KB LDS (scratch reuses it after one barrier),
// 2 blocks/CU = 8 waves/CU. VGPR peak ~210 -> 2 waves/SIMD, no spill.
// Predicted: kernel 5.8 -> ~4.3 us; dur_us 66.0 -> 64.3-65.0.

__global__ __launch_bounds__(256, 2)
void tropical_linear_kernel(const float* __restrict__ x,
                            const float* __restrict__ w,
                            const float* __restrict__ bias,
                            float* __restrict__ out) {
    // 64 KB: w-panel (16 o-rows x 256 f4); reused post-barrier as 4
    // per-wave scratchpads of 64 lanes x 36 words (9216 B each).
    __shared__ float lds_raw[16384];
    float4* wlds = (float4*)lds_raw;

    const int tid  = threadIdx.x;
    const int wid  = tid >> 6;       // wave 0..3 -> n-rows wid*4..+3
    const int lane = tid & 63;
    const int h    = lane >> 5;      // o-half: rows h*8..h*8+7
    const int g    = lane & 31;      // k-slice owner: f4s {t*32+g}

    const int bn = blockIdx.x >> 6;  // 8 n-blocks
    const int bo = blockIdx.x & 63;  // 64 o-blocks (idx%8==bo%8 -> same XCD)
    const int n0 = bn * 16;
    const int o0 = bo * 16;

    // ---- stage w panel: 4096 f4, 16 per thread, coalesced ----
    const float4* __restrict__ wg = (const float4*)w + (size_t)o0 * 256;
#pragma unroll
    for (int i = 0; i < 16; ++i) {
        const int idx = tid + i * 256;
        wlds[idx] = wg[idx];
    }

    // ---- x -> registers: 4 rows x 8 f4 per lane (halves duplicate the
    //      same addresses in-instruction -> no extra L2/HBM bytes) ----
    const float4* __restrict__ xg =
        (const float4*)x + (size_t)(n0 + wid * 4) * 256 + g;
    float4 xr[4][8];
#pragma unroll
    for (int j = 0; j < 4; ++j)
#pragma unroll
        for (int t = 0; t < 8; ++t)
            xr[j][t] = xg[j * 256 + t * 32];

    float acc[4][8];
#pragma unroll
    for (int j = 0; j < 4; ++j)
#pragma unroll
        for (int ol = 0; ol < 8; ++ol) acc[j][ol] = -3.4e38f;

    __syncthreads();   // w-panel visible to all waves

    // ---- main loop: 8 o-rows per half, all offsets LDS-imm-foldable ----
    const float4* __restrict__ wlh = wlds + (size_t)(h * 8) * 256 + g;
#pragma unroll
    for (int ol = 0; ol < 8; ++ol) {
        float4 wv[8];
#pragma unroll
        for (int t = 0; t < 8; ++t) wv[t] = wlh[ol * 256 + t * 32];
#pragma unroll
        for (int j = 0; j < 4; ++j)
#pragma unroll
            for (int t = 0; t < 8; ++t) {
                const float4 xv = xr[j][t];
                const float s0 = wv[t].x + xv.x;
                const float s1 = wv[t].y + xv.y;
                const float s2 = wv[t].z + xv.z;
                const float s3 = wv[t].w + xv.w;
                const float m = fmaxf(fmaxf(s0, s1), s2);     // v_max3
                acc[j][ol] = fmaxf(fmaxf(m, s3), acc[j][ol]); // v_max3
            }
    }

    // ---- k-reduce: 32 partials/output via padded per-wave scratch ----
    __syncthreads();   // all waves done reading the panel; safe to reuse
    float* scr = lds_raw + wid * (64 * 36);
    float4* scr4 = (float4*)scr;     // lane row = 9 f4 (36 words, 16B-aligned)

    // write: lane's 32 values (v = j*8 + ol) as 8 b128; banks native
#pragma unroll
    for (int j = 0; j < 4; ++j) {
        scr4[lane * 9 + j * 2 + 0] =
            make_float4(acc[j][0], acc[j][1], acc[j][2], acc[j][3]);
        scr4[lane * 9 + j * 2 + 1] =
            make_float4(acc[j][4], acc[j][5], acc[j][6], acc[j][7]);
    }
    // same-wave LDS RAW: in-order LDS pipe + compiler lgkmcnt (R9-validated)

    // read+fold: lane p owns output (j=p>>4, o=p&15); its 32 partials sit
    // at rows (h(o)*32 + s), word v = j*8 + (o&7). Banks (4s+v)%32: 2-way.
    {
        const int jj = lane >> 4;
        const int oo = lane & 15;
        const int hh = oo >> 3;
        const int vv = jj * 8 + (oo & 7);
        const float* base = scr + (size_t)(hh * 32) * 36 + vv;
        float m0 = -3.4e38f, m1 = -3.4e38f, m2 = -3.4e38f, m3 = -3.4e38f;
#pragma unroll
        for (int s = 0; s < 32; s += 4) {
            m0 = fmaxf(m0, base[(s + 0) * 36]);
            m1 = fmaxf(m1, base[(s + 1) * 36]);
            m2 = fmaxf(m2, base[(s + 2) * 36]);
            m3 = fmaxf(m3, base[(s + 3) * 36]);
        }
        const float m = fmaxf(fmaxf(m0, m1), fmaxf(m2, m3));
        const int o = o0 + oo;
        out[(size_t)(n0 + wid * 4 + jj) * OUT_DIM + o] = m + bias[o];
    }
}

extern "C" void kernel_launch(void* const* d_in, const int* in_sizes, int n_in,
                              void* d_out, int out_size, void* d_ws, size_t ws_size,
                              hipStream_t stream) {
    const float* x    = (const float*)d_in[0];   // [128,1024]
    const float* w    = (const float*)d_in[1];   // [1024,1024]
    const float* bias = (const float*)d_in[2];   // [1024]
    float* out = (float*)d_out;                  // [128,1024]

    dim3 grid(512);
    dim3 block(256);
    hipLaunchKernelGGL(tropical_linear_kernel, grid, block, 0, stream,
                       x, w, bias, out);
}